// Round 1
// baseline (1334.061 us; speedup 1.0000x reference)
//
#include <hip/hip_runtime.h>
#include <math.h>

typedef unsigned short u16;
typedef __attribute__((ext_vector_type(8))) short bfrag;   // 8 bf16 (4 VGPRs)
typedef __attribute__((ext_vector_type(4))) float f32x4;   // 4 fp32 acc

#define MFMA(a,b,c) __builtin_amdgcn_mfma_f32_16x16x32_bf16((a),(b),(c),0,0,0)

#define DIMC 256
#define WC 64
#define HC 8
#define HIDC 1024
// ws layout (u16 element offsets)
#define OFF_QKVWT 0         // [768][256]
#define OFF_PROJWT 196608   // [256][256]
#define OFF_W1T   262144    // [1024][256]
#define OFF_W2T   524288    // [256][1024]

__device__ __forceinline__ float bf2f(u16 u){
  unsigned int i = ((unsigned int)u) << 16; float f; __builtin_memcpy(&f,&i,4); return f;
}
__device__ __forceinline__ u16 f2bf(float f){
  unsigned int i; __builtin_memcpy(&i,&f,4);
  i += 0x7FFFu + ((i >> 16) & 1u); return (u16)(i >> 16);
}

// ---------- K0: weight transpose+cast fp32 -> bf16 [out_col][k] in d_ws ----------
__global__ __launch_bounds__(256) void k_prep(const float* __restrict__ qkvw,
    const float* __restrict__ projw, const float* __restrict__ w1,
    const float* __restrict__ w2, u16* __restrict__ ws){
  int gid = blockIdx.x*256 + threadIdx.x;
  if (gid < 196608){                       // qkvwt[j][k] = qkvw[k][j]
    int j = gid >> 8, k = gid & 255;
    ws[OFF_QKVWT + gid] = f2bf(qkvw[(size_t)k*768 + j]);
  } else if (gid < 262144){                // projwt
    int g = gid - 196608; int j = g >> 8, k = g & 255;
    ws[OFF_PROJWT + g] = f2bf(projw[(size_t)k*256 + j]);
  } else if (gid < 524288){                // w1t
    int g = gid - 262144; int j = g >> 8, k = g & 255;
    ws[OFF_W1T + g] = f2bf(w1[(size_t)k*1024 + j]);
  } else {                                 // w2t[j][k] = w2[k][j], j<256,k<1024
    int g = gid - 524288; int j = g >> 10, k = g & 1023;
    ws[OFF_W2T + g] = f2bf(w2[(size_t)k*256 + j]);
  }
}

// ---------------- K1: LayerNorm1 over all tokens (fp32 -> fp32 d_out) ----------------
__global__ __launch_bounds__(256) void k_ln1(const float* __restrict__ x,
                                             const float* __restrict__ g,
                                             const float* __restrict__ b,
                                             float* __restrict__ out, int ntok){
  const int lane = threadIdx.x & 63;
  const int wv = threadIdx.x >> 6;
  const long long t = (long long)blockIdx.x * 4 + wv;
  if (t >= ntok) return;
  float4 v = ((const float4*)(x + t * DIMC))[lane];
  float s = v.x + v.y + v.z + v.w;
  #pragma unroll
  for (int o = 32; o; o >>= 1) s += __shfl_xor(s, o);
  float mu = s * (1.0f/256.0f);
  float d0 = v.x-mu, d1 = v.y-mu, d2 = v.z-mu, d3 = v.w-mu;
  float q = d0*d0 + d1*d1 + d2*d2 + d3*d3;
  #pragma unroll
  for (int o = 32; o; o >>= 1) q += __shfl_xor(q, o);
  float rs = rsqrtf(q * (1.0f/256.0f) + 1e-5f);
  float4 gv = ((const float4*)g)[lane];
  float4 bv = ((const float4*)b)[lane];
  float4 ov;
  ov.x = d0*rs*gv.x + bv.x; ov.y = d1*rs*gv.y + bv.y;
  ov.z = d2*rs*gv.z + bv.z; ov.w = d3*rs*gv.w + bv.w;
  ((float4*)(out + t * DIMC))[lane] = ov;
}

// ------------- K2: per-window MFMA qkv + attention + proj + residual -------------
// v2: qkv B-frags direct from global (L2-resident), A-frags hoisted to registers,
//     Ob un-aliased from qb -> only cross-wave LDS is kb/vt -> 2 barriers/head.
__global__ __launch_bounds__(256) void k_attn(const int* __restrict__ idx,
    const u16* __restrict__ qkvwt, const float* __restrict__ qkvb,
    const u16* __restrict__ projwt, const float* __restrict__ projb,
    float* __restrict__ Y){
  __shared__ __align__(16) u16 smem[31488];      // 62976 B (2 blocks/CU)
  u16* xs = smem;                  // [64][264] x-hat bf16 (wave-private rows)
  u16* Pb = smem + 16896;          // [64][72]  P (wave-private rows)
  u16* qb = Pb + 4608;             // [64][40]  (wave-private rows)
  u16* kb = qb + 2560;             // [64][40]  (cross-wave)
  u16* Ob = kb + 2560;             // [64][40]  (wave-private rows)
  u16* vt = Ob + 2560;             // [32][72]  v transposed (cross-wave)

  const int tid = threadIdx.x, lane = tid & 63, w = tid >> 6;
  const int quad = lane >> 4, l16 = lane & 15;
  const long long row0 = (long long)idx[blockIdx.x] * (WC * DIMC);
  const f32x4 z = {0.f,0.f,0.f,0.f};

  // xs: read fp32 X rows, store bf16 (wave w: tokens 16w..16w+15; own rows only)
  #pragma unroll
  for (int t = 0; t < 16; ++t){
    int tok = 16*w + t;
    float4 v = ((const float4*)(Y + row0 + (long long)tok*DIMC))[lane];
    ushort4 o; o.x=f2bf(v.x); o.y=f2bf(v.y); o.z=f2bf(v.z); o.w=f2bf(v.w);
    *(ushort4*)(xs + tok*264 + lane*4) = o;
  }
  // hoist A-frags: row l16+16w covers K=256 in 8 frags; reused for all heads/q/k/v
  bfrag axs[8];
  #pragma unroll
  for (int ks = 0; ks < 8; ++ks)
    axs[ks] = *(const bfrag*)(xs + (l16+16*w)*264 + ks*32 + quad*8);

  f32x4 accP[16];
  #pragma unroll
  for (int nt = 0; nt < 16; ++nt) accP[nt] = z;

  for (int h = 0; h < HC; ++h){
    // ---- q,k,v via MFMA; B-frags direct from global qkvwt (L2-resident) ----
    #pragma unroll
    for (int which = 0; which < 3; ++which){
      const int cb = h*96 + which*32;
      const u16* wb = qkvwt + (size_t)cb*256;
      f32x4 c0 = z, c1 = z;
      #pragma unroll
      for (int ks = 0; ks < 8; ++ks){
        bfrag b0 = *(const bfrag*)(wb + (size_t)l16*256      + ks*32 + quad*8);
        bfrag b1 = *(const bfrag*)(wb + (size_t)(l16+16)*256 + ks*32 + quad*8);
        c0 = MFMA(axs[ks], b0, c0); c1 = MFMA(axs[ks], b1, c1);
      }
      float bi0 = qkvb[cb + l16], bi1 = qkvb[cb + 16 + l16];
      if (which < 2){
        u16* dst = which ? kb : qb;
        #pragma unroll
        for (int r = 0; r < 4; ++r){
          int row = quad*4 + r + 16*w;
          dst[row*40 + l16]      = f2bf(c0[r] + bi0);
          dst[row*40 + 16 + l16] = f2bf(c1[r] + bi1);
        }
      } else {
        #pragma unroll
        for (int r = 0; r < 4; ++r){
          int row = quad*4 + r + 16*w;
          vt[l16*72 + row]      = f2bf(c0[r] + bi0);
          vt[(16+l16)*72 + row] = f2bf(c1[r] + bi1);
        }
      }
    }
    __syncthreads();   // barrier 1: kb/vt (cross-wave) ready
    // ---- S = q k^T (qb rows are wave-private) ----
    bfrag aq = *(const bfrag*)(qb + (l16+16*w)*40 + quad*8);
    f32x4 s[4];
    #pragma unroll
    for (int nt = 0; nt < 4; ++nt){
      bfrag bk = *(const bfrag*)(kb + (l16+16*nt)*40 + quad*8);
      s[nt] = MFMA(aq, bk, z);
    }
    // ---- softmax in C-layout registers ----
    float p[4][4];
    #pragma unroll
    for (int r = 0; r < 4; ++r){
      const float SC = 0.17677669529663687f;
      float v0 = s[0][r]*SC, v1 = s[1][r]*SC, v2 = s[2][r]*SC, v3 = s[3][r]*SC;
      float mx = fmaxf(fmaxf(v0,v1), fmaxf(v2,v3));
      #pragma unroll
      for (int o = 1; o <= 8; o <<= 1) mx = fmaxf(mx, __shfl_xor(mx, o));
      float e0 = __expf(v0-mx), e1 = __expf(v1-mx), e2 = __expf(v2-mx), e3 = __expf(v3-mx);
      float sm = e0+e1+e2+e3;
      #pragma unroll
      for (int o = 1; o <= 8; o <<= 1) sm += __shfl_xor(sm, o);
      float inv = 1.0f / sm;
      p[0][r]=e0*inv; p[1][r]=e1*inv; p[2][r]=e2*inv; p[3][r]=e3*inv;
    }
    // ---- P -> LDS (wave-private rows, no barrier needed) ----
    #pragma unroll
    for (int nt = 0; nt < 4; ++nt)
      #pragma unroll
      for (int r = 0; r < 4; ++r)
        Pb[(quad*4 + r + 16*w)*72 + l16 + 16*nt] = f2bf(p[nt][r]);
    // ---- O = P V (ap wave-private; bv cross-wave, covered by barrier 1) ----
    f32x4 o0 = z, o1 = z;
    #pragma unroll
    for (int ks = 0; ks < 2; ++ks){
      bfrag ap  = *(const bfrag*)(Pb + (l16+16*w)*72 + ks*32 + quad*8);
      bfrag bv0 = *(const bfrag*)(vt + l16*72      + ks*32 + quad*8);
      bfrag bv1 = *(const bfrag*)(vt + (16+l16)*72 + ks*32 + quad*8);
      o0 = MFMA(ap, bv0, o0); o1 = MFMA(ap, bv1, o1);
    }
    __syncthreads();   // barrier 2: all cross-wave reads of kb/vt done -> next head may overwrite
    // ---- O -> Ob (wave-private), proj accumulate (B direct from global) ----
    #pragma unroll
    for (int r = 0; r < 4; ++r){
      int row = quad*4 + r + 16*w;
      Ob[row*40 + l16]      = f2bf(o0[r]);
      Ob[row*40 + 16 + l16] = f2bf(o1[r]);
    }
    bfrag ao = *(const bfrag*)(Ob + (l16+16*w)*40 + quad*8);
    #pragma unroll
    for (int nt = 0; nt < 16; ++nt){
      bfrag bp = *(const bfrag*)(projwt + (size_t)(l16+16*nt)*256 + h*32 + quad*8);
      accP[nt] = MFMA(ao, bp, accP[nt]);
    }
  }
  // epilogue: Y += accP + projb (residual X already in Y, fp32)
  #pragma unroll
  for (int nt = 0; nt < 16; ++nt){
    int col = l16 + 16*nt;
    float pbv = projb[col];
    #pragma unroll
    for (int r = 0; r < 4; ++r){
      int row = quad*4 + r + 16*w;
      long long a = row0 + (long long)row*DIMC + col;
      Y[a] = Y[a] + accP[nt][r] + pbv;
    }
  }
}

// ------------- K3: per-window MFMA LN2 + fc1 + gelu + fc2 + residual -------------
// v2: 64-col hidden chunks (16 iters, 32 barriers instead of 64); wave w owns
//     col-tile w of each chunk -> no cross-wave redundancy on fc1 B reads.
__global__ __launch_bounds__(256) void k_mlp(const int* __restrict__ idx,
    const float* __restrict__ g2, const float* __restrict__ b2,
    const u16* __restrict__ w1t, const float* __restrict__ b1,
    const u16* __restrict__ w2t, const float* __restrict__ fc2b,
    float* __restrict__ Y){
  __shared__ __align__(16) u16 hb[WC*264];   // 33792 B: LN2(h) bf16
  __shared__ __align__(16) u16 gb[WC*72];    // 9216 B: gelu chunk [64][72]

  const int tid = threadIdx.x, lane = tid & 63, w = tid >> 6;
  const int quad = lane >> 4, l16 = lane & 15;
  const long long row0 = (long long)idx[blockIdx.x] * (WC * DIMC);
  const f32x4 z = {0.f,0.f,0.f,0.f};

  // acc init: residual h (fp32 from Y) + fc2 bias, in C-layout (wave w: nt w*4..w*4+3)
  f32x4 acc[4][4];  // [mt][i]
  #pragma unroll
  for (int mt = 0; mt < 4; ++mt)
    #pragma unroll
    for (int i = 0; i < 4; ++i){
      int col = l16 + 16*(w*4 + i);
      float bb = fc2b[col];
      f32x4 a;
      #pragma unroll
      for (int r = 0; r < 4; ++r)
        a[r] = Y[row0 + (long long)(quad*4 + r + 16*mt)*DIMC + col] + bb;
      acc[mt][i] = a;
    }
  // LN2 -> hb bf16 (wave w: tokens 16w..16w+15)
  {
    float4 gv = ((const float4*)g2)[lane];
    float4 bv = ((const float4*)b2)[lane];
    for (int t = 0; t < 16; ++t){
      int tok = 16*w + t;
      float4 v = ((const float4*)(Y + row0 + (long long)tok*DIMC))[lane];
      float s = v.x+v.y+v.z+v.w;
      #pragma unroll
      for (int o = 32; o; o >>= 1) s += __shfl_xor(s, o);
      float mu = s*(1.f/256.f);
      float d0=v.x-mu,d1=v.y-mu,d2=v.z-mu,d3=v.w-mu;
      float q = d0*d0+d1*d1+d2*d2+d3*d3;
      #pragma unroll
      for (int o = 32; o; o >>= 1) q += __shfl_xor(q, o);
      float rs = rsqrtf(q*(1.f/256.f)+1e-5f);
      ushort4 ou;
      ou.x=f2bf(d0*rs*gv.x+bv.x); ou.y=f2bf(d1*rs*gv.y+bv.y);
      ou.z=f2bf(d2*rs*gv.z+bv.z); ou.w=f2bf(d3*rs*gv.w+bv.w);
      *(ushort4*)(hb + tok*264 + lane*4) = ou;
    }
  }
  __syncthreads();

  for (int ch = 0; ch < 16; ++ch){
    // fc1: wave w covers chunk cols [16w,16w+16), all 4 m-tiles; B direct from global
    const int colL = l16 + 16*w;               // col within 64-wide chunk
    const int gcol = ch*64 + colL;
    f32x4 f1[4] = {z, z, z, z};
    const u16* bp = w1t + (size_t)gcol*256;
    #pragma unroll
    for (int ks = 0; ks < 8; ++ks){
      bfrag bw = *(const bfrag*)(bp + ks*32 + quad*8);
      #pragma unroll
      for (int mt = 0; mt < 4; ++mt){
        bfrag am = *(const bfrag*)(hb + (l16+16*mt)*264 + ks*32 + quad*8);
        f1[mt] = MFMA(am, bw, f1[mt]);
      }
    }
    float bias = b1[gcol];
    #pragma unroll
    for (int mt = 0; mt < 4; ++mt)
      #pragma unroll
      for (int r = 0; r < 4; ++r){
        float xg = f1[mt][r] + bias;
        float ge = 0.5f*xg*(1.f + erff(xg*0.70710678118654752f));
        gb[(quad*4 + r + 16*mt)*72 + colL] = f2bf(ge);
      }
    __syncthreads();
    // fc2: K=64 (2 ksteps); A from gb (cross-wave), B direct from global w2t
    #pragma unroll
    for (int ks = 0; ks < 2; ++ks){
      bfrag av[4];
      #pragma unroll
      for (int mt = 0; mt < 4; ++mt)
        av[mt] = *(const bfrag*)(gb + (l16+16*mt)*72 + ks*32 + quad*8);
      #pragma unroll
      for (int i = 0; i < 4; ++i){
        int nt = w*4 + i;
        bfrag bw2 = *(const bfrag*)(w2t + (size_t)(l16+16*nt)*1024 + ch*64 + ks*32 + quad*8);
        #pragma unroll
        for (int mt = 0; mt < 4; ++mt)
          acc[mt][i] = MFMA(av[mt], bw2, acc[mt][i]);
      }
    }
    __syncthreads();
  }
  // epilogue
  #pragma unroll
  for (int mt = 0; mt < 4; ++mt)
    #pragma unroll
    for (int i = 0; i < 4; ++i){
      int col = l16 + 16*(w*4 + i);
      #pragma unroll
      for (int r = 0; r < 4; ++r)
        Y[row0 + (long long)(quad*4 + r + 16*mt)*DIMC + col] = acc[mt][i][r];
    }
}

extern "C" void kernel_launch(void* const* d_in, const int* in_sizes, int n_in,
                              void* d_out, int out_size, void* d_ws, size_t ws_size,
                              hipStream_t stream) {
  const float* x    = (const float*)d_in[0];
  const int*   idx  = (const int*)d_in[1];
  const int    M    = in_sizes[1];
  const float* n1g  = (const float*)d_in[3];
  const float* n1b  = (const float*)d_in[4];
  const float* qkvw = (const float*)d_in[5];
  const float* qkvb = (const float*)d_in[6];
  const float* pw   = (const float*)d_in[7];
  const float* pb   = (const float*)d_in[8];
  const float* n2g  = (const float*)d_in[9];
  const float* n2b  = (const float*)d_in[10];
  const float* w1   = (const float*)d_in[11];
  const float* b1   = (const float*)d_in[12];
  const float* w2   = (const float*)d_in[13];
  const float* b2   = (const float*)d_in[14];
  float* out = (float*)d_out;
  u16* ws = (u16*)d_ws;
  const int ntok = out_size / DIMC;

  k_prep<<<3072, 256, 0, stream>>>(qkvw, pw, w1, w2, ws);
  k_ln1<<<(ntok + 3) / 4, 256, 0, stream>>>(x, n1g, n1b, out, ntok);
  k_attn<<<M, 256, 0, stream>>>(idx, ws + OFF_QKVWT, qkvb, ws + OFF_PROJWT, pb, out);
  k_mlp<<<M, 256, 0, stream>>>(idx, n2g, n2b, ws + OFF_W1T, b1, ws + OFF_W2T, b2, out);
}